// Round 1
// baseline (349.469 us; speedup 1.0000x reference)
//
#include <hip/hip_runtime.h>
#include <math.h>

typedef _Float16 f16;
typedef _Float16 f16x8 __attribute__((ext_vector_type(8)));
typedef float f32x4 __attribute__((ext_vector_type(4)));

#define LSEQ 200
#define LT 13     // l-tiles of 16 (padded 208)
#define LKS 7     // k-steps over l padded to 224

// One block per sample n. 256 threads = 4 waves.
// LDS fragment layouts: everything stored as 16B chunks so that MFMA wave
// lane i reads chunk i of a superblock => conflict-free ds_read_b128.
__global__ __launch_bounds__(256, 2)
void capsule_kernel(const float* __restrict__ E,   // [N,200,64]
                    const float* __restrict__ W,   // [64,64]
                    const float* __restrict__ RL,  // [N,3,200]
                    const int* __restrict__ SL,    // [N]
                    float* __restrict__ out)       // [N,3,64]
{
    __shared__ f16 E_sw[LT*2*64*8];     // 26624 B: E frags; reused as mappings row-frag
    __shared__ f16 W_sw[4*2*64*8];      //  8192 B
    __shared__ f16 mT_sw[4*LKS*64*8];   // 28672 B: mappings^T frags (l contiguous)
    __shared__ f16 w_sw[LKS*64*8];      //  7168 B: routing weights frags [16 k-rows][224 l]
    __shared__ f16 i_sw[2*64*8];        //  2048 B: interests frags [16 k-rows][64 o]
    __shared__ float logits[3*LSEQ];    //  2400 B
    __shared__ float cand[3*64];        //   768 B

    const int n = blockIdx.x;
    const int t = threadIdx.x;
    const int lane = t & 63;
    const int wv = t >> 6;

    const float4 f4z = make_float4(0.f, 0.f, 0.f, 0.f);
    // zero-init pads (k-rows 3..15, l 200..223) once; real slots rewritten each iter
    for (int g = t; g < 448;  g += 256) *(float4*)&w_sw[g*8]  = f4z;
    for (int g = t; g < 128;  g += 256) *(float4*)&i_sw[g*8]  = f4z;
    for (int g = t; g < 1792; g += 256) *(float4*)&mT_sw[g*8] = f4z;

    // ---- stage E (fp32 -> f16, fragment-swizzled). Pad rows 200..207 = 0.
    const float* Eb = E + (size_t)n * (LSEQ*64);
    for (int g = t; g < LT*2*64; g += 256) {
        int sb = g >> 6, c = g & 63;
        int Tl = sb >> 1, ks = sb & 1;
        int q = c >> 4, m = c & 15;
        int l = Tl*16 + m;
        int kb = ks*32 + q*8;
        float4 v0 = f4z, v1 = f4z;
        if (l < LSEQ) {
            v0 = *(const float4*)(Eb + l*64 + kb);
            v1 = *(const float4*)(Eb + l*64 + kb + 4);
        }
        f16x8 h = { (f16)v0.x,(f16)v0.y,(f16)v0.z,(f16)v0.w,
                    (f16)v1.x,(f16)v1.y,(f16)v1.z,(f16)v1.w };
        *(f16x8*)&E_sw[g*8] = h;
    }

    // ---- stage W (B-operand frags: k=d contiguous per lane => read W columns)
    for (int g = t; g < 512; g += 256) {
        int sb = g >> 6, c = g & 63;
        int To = sb >> 1, ks = sb & 1;
        int q = c >> 4, m = c & 15;
        int o = To*16 + m;
        int d0 = ks*32 + q*8;
        f16x8 h;
        #pragma unroll
        for (int j = 0; j < 8; j++) h[j] = (f16)W[(d0 + j)*64 + o];
        *(f16x8*)&W_sw[g*8] = h;
    }

    // ---- stage logits
    if (t < LSEQ) {
        const float* R = RL + (size_t)n * (3*LSEQ);
        logits[t]          = R[t];
        logits[LSEQ + t]   = R[LSEQ + t];
        logits[2*LSEQ + t] = R[2*LSEQ + t];
    }
    const int s = SL[n];

    __syncthreads();

    // ---- main matmul: mappings = E @ W. wave wv owns o-tile To=wv, 13 l-tiles.
    f32x4 acc[LT];
    {
        const int To = wv;
        #pragma unroll
        for (int Tl = 0; Tl < LT; Tl++) {
            f32x4 c0 = {0.f, 0.f, 0.f, 0.f};
            #pragma unroll
            for (int ks = 0; ks < 2; ks++) {
                f16x8 a = *(f16x8*)&E_sw[((Tl*2 + ks)*64 + lane)*8];
                f16x8 b = *(f16x8*)&W_sw[((To*2 + ks)*64 + lane)*8];
                c0 = __builtin_amdgcn_mfma_f32_16x16x32_f16(a, b, c0, 0, 0, 0);
            }
            acc[Tl] = c0;
        }
    }
    __syncthreads();   // all E_sw reads complete before overlay writes

    // ---- epilogue: D frag (row=(lane>>4)*4+reg, col=lane&15) -> f16
    //      write row-major frags into E_sw (for delta) and transposed frags into mT_sw
    {
        const int To = wv;
        const int q4 = lane >> 4, cc = lane & 15;
        const int o = To*16 + cc;
        const int kso = o >> 5, qo = (o & 31) >> 3, jo = o & 7;
        #pragma unroll
        for (int Tl = 0; Tl < LT; Tl++) {
            #pragma unroll
            for (int r = 0; r < 4; r++) {
                f16 h = (f16)acc[Tl][r];
                int lp = q4*4 + r;          // row within l-tile
                int l  = Tl*16 + lp;
                E_sw [((Tl*2 + kso)*64 + qo*16 + lp)*8 + jo] = h;
                mT_sw[((To*LKS + (l >> 5))*64 + ((l & 31) >> 3)*16 + cc)*8 + (lp & 7)] = h;
            }
        }
    }
    __syncthreads();

    // ---- routing: 3 iterations (2 with logits update, last writes output)
    for (int iter = 0; iter < 3; iter++) {
        // softmax over k (3 capsules) per position l; masked l -> uniform 1/3
        if (t < LSEQ) {
            float w0, w1, w2;
            if (t < s) {
                float l0 = logits[t], l1 = logits[LSEQ + t], l2 = logits[2*LSEQ + t];
                float mx = fmaxf(fmaxf(l0, l1), l2);
                float e0 = expf(l0 - mx), e1 = expf(l1 - mx), e2 = expf(l2 - mx);
                float inv = 1.f / (e0 + e1 + e2);
                w0 = e0*inv; w1 = e1*inv; w2 = e2*inv;
            } else {
                w0 = w1 = w2 = (1.f/3.f);
            }
            int ks = t >> 5, q = (t & 31) >> 3, j = t & 7;
            int base = (ks*64 + q*16)*8 + j;
            w_sw[base]      = (f16)w0;
            w_sw[base + 8]  = (f16)w1;
            w_sw[base + 16] = (f16)w2;
        }
        __syncthreads();

        // candidates[k][o] = sum_l w[k][l]*m[l][o]  (MFMA, contract l=224)
        f32x4 ca = {0.f, 0.f, 0.f, 0.f};
        #pragma unroll
        for (int ks = 0; ks < LKS; ks++) {
            f16x8 a = *(f16x8*)&w_sw[(ks*64 + lane)*8];
            f16x8 b = *(f16x8*)&mT_sw[((wv*LKS + ks)*64 + lane)*8];
            ca = __builtin_amdgcn_mfma_f32_16x16x32_f16(a, b, ca, 0, 0, 0);
        }
        if (lane < 16) {
            #pragma unroll
            for (int r = 0; r < 3; r++) cand[r*64 + wv*16 + lane] = ca[r];
        }
        __syncthreads();

        // squash per capsule k (waves 0..2), write interests or final output
        if (t < 192) {
            float x = cand[t];
            float sq = x*x;
            #pragma unroll
            for (int off = 32; off >= 1; off >>= 1) sq += __shfl_xor(sq, off, 64);
            float factor = sq / ((1.f + sq) * sqrtf(sq + 1e-8f));
            float y = factor * x;
            if (iter < 2) {
                int k = t >> 6, o = t & 63;
                i_sw[(((o >> 5)*4 + ((o & 31) >> 3))*16 + k)*8 + (o & 7)] = (f16)y;
            } else {
                out[(size_t)n*192 + t] = y;
            }
        }
        if (iter == 2) break;
        __syncthreads();

        // logits[k][l] += sum_o interests[k][o]*m[l][o]  (MFMA, contract o=64)
        for (int Tn = wv; Tn < LT; Tn += 4) {
            f32x4 da = {0.f, 0.f, 0.f, 0.f};
            #pragma unroll
            for (int kso = 0; kso < 2; kso++) {
                f16x8 a = *(f16x8*)&i_sw[(kso*64 + lane)*8];
                f16x8 b = *(f16x8*)&E_sw[((Tn*2 + kso)*64 + lane)*8];
                da = __builtin_amdgcn_mfma_f32_16x16x32_f16(a, b, da, 0, 0, 0);
            }
            if (lane < 16) {
                int l = Tn*16 + lane;
                if (l < LSEQ) {
                    logits[l]          += da[0];
                    logits[LSEQ + l]   += da[1];
                    logits[2*LSEQ + l] += da[2];
                }
            }
        }
        __syncthreads();
    }
}

extern "C" void kernel_launch(void* const* d_in, const int* in_sizes, int n_in,
                              void* d_out, int out_size, void* d_ws, size_t ws_size,
                              hipStream_t stream) {
    const float* E  = (const float*)d_in[0];
    const float* W  = (const float*)d_in[1];
    const float* RL = (const float*)d_in[2];
    const int*   SL = (const int*)d_in[3];
    float* o = (float*)d_out;
    const int N = in_sizes[3];   // seq_len has N entries
    capsule_kernel<<<dim3(N), dim3(256), 0, stream>>>(E, W, RL, SL, o);
}

// Round 2
// 313.390 us; speedup vs baseline: 1.1151x; 1.1151x over previous
//
#include <hip/hip_runtime.h>
#include <math.h>

typedef _Float16 f16;
typedef _Float16 f16x8 __attribute__((ext_vector_type(8)));
typedef float f32x4 __attribute__((ext_vector_type(4)));

#define LSEQ 200
#define LT 13     // l-tiles of 16 (padded 208)
#define LKS 7     // k-steps over l padded to 224

// One block per sample n. 256 threads = 4 waves.
// LDS cut to 39 KB -> 4 blocks/CU (R1 was 76 KB -> 2 blocks/CU, latency-bound).
// mappings^T fragments live in per-wave REGISTERS (each wave only needs its own
// o-tile as the cand A-operand); W B-frags loaded direct from global (L2-hot).
__global__ __launch_bounds__(256, 4)
void capsule_kernel(const float* __restrict__ E,   // [N,200,64]
                    const float* __restrict__ W,   // [64,64]
                    const float* __restrict__ RL,  // [N,3,200]
                    const int* __restrict__ SL,    // [N]
                    float* __restrict__ out)       // [N,3,64]
{
    __shared__ f16 m_sw[LT*2*64*8];     // 26624 B: E frags; reused as mappings row-frag
    __shared__ f16 w_sw[LKS*64*8];      //  7168 B: routing weights frags [16 rows][224 l]
    __shared__ f16 i_sw[2*64*8];        //  2048 B: interests frags [16 rows][64 o]
    __shared__ float logits[3*LSEQ];    //  2400 B
    __shared__ float cand[3*64];        //   768 B
    // total 39008 B -> 4 blocks/CU

    const int n = blockIdx.x;
    const int t = threadIdx.x;
    const int lane = t & 63;
    const int wv = t >> 6;
    const int q = lane >> 4;      // quad
    const int cc = lane & 15;     // column within MFMA tile

    // ---- W B-frags for this wave's o-tile, direct from global (16 KB, L2-hot)
    const int o_own = wv*16 + cc;
    float wf[16];
    #pragma unroll
    for (int ks = 0; ks < 2; ks++)
        #pragma unroll
        for (int j = 0; j < 8; j++)
            wf[ks*8 + j] = W[(ks*32 + q*8 + j)*64 + o_own];

    const float4 f4z = make_float4(0.f, 0.f, 0.f, 0.f);
    // zero pads once: w_sw (l 200..223 stay 0), i_sw (rows 3..15 stay 0)
    for (int g = t; g < 448; g += 256) *(float4*)&w_sw[g*8] = f4z;
    for (int g = t; g < 128; g += 256) *(float4*)&i_sw[g*8] = f4z;

    // ---- stage E (fp32 -> f16, A-fragment-swizzled). Pad rows 200..207 = 0.
    const float* Eb = E + (size_t)n * (LSEQ*64);
    for (int g = t; g < LT*2*64; g += 256) {
        int sb = g >> 6, c = g & 63;
        int Tl = sb >> 1, ks = sb & 1;
        int qq = c >> 4, m = c & 15;
        int l = Tl*16 + m;
        int kb = ks*32 + qq*8;
        float4 v0 = f4z, v1 = f4z;
        if (l < LSEQ) {
            v0 = *(const float4*)(Eb + l*64 + kb);
            v1 = *(const float4*)(Eb + l*64 + kb + 4);
        }
        f16x8 h = { (f16)v0.x,(f16)v0.y,(f16)v0.z,(f16)v0.w,
                    (f16)v1.x,(f16)v1.y,(f16)v1.z,(f16)v1.w };
        *(f16x8*)&m_sw[g*8] = h;
    }

    // ---- stage logits
    if (t < LSEQ) {
        const float* R = RL + (size_t)n * (3*LSEQ);
        logits[t]          = R[t];
        logits[LSEQ + t]   = R[LSEQ + t];
        logits[2*LSEQ + t] = R[2*LSEQ + t];
    }
    const int s = SL[n];

    __syncthreads();

    // ---- main matmul: mappings = E @ W. wave wv owns o-tile wv, 13 l-tiles.
    f16x8 wB[2];
    #pragma unroll
    for (int ks = 0; ks < 2; ks++) {
        f16x8 h;
        #pragma unroll
        for (int j = 0; j < 8; j++) h[j] = (f16)wf[ks*8 + j];
        wB[ks] = h;
    }
    f32x4 acc[LT];
    #pragma unroll
    for (int Tl = 0; Tl < LT; Tl++) {
        f32x4 c0 = {0.f, 0.f, 0.f, 0.f};
        #pragma unroll
        for (int ks = 0; ks < 2; ks++) {
            f16x8 a = *(f16x8*)&m_sw[((Tl*2 + ks)*64 + lane)*8];
            c0 = __builtin_amdgcn_mfma_f32_16x16x32_f16(a, wB[ks], c0, 0, 0, 0);
        }
        acc[Tl] = c0;
    }
    __syncthreads();   // all E reads complete before overlay writes

    // ---- epilogue: D frag (row=q*4+r, col=cc) -> f16 row-frag m in m_sw
    const int kso = o_own >> 5, qo = (o_own & 31) >> 3, jo = o_own & 7;
    #pragma unroll
    for (int Tl = 0; Tl < LT; Tl++) {
        #pragma unroll
        for (int r = 0; r < 4; r++) {
            int lp = q*4 + r;
            m_sw[((Tl*2 + kso)*64 + qo*16 + lp)*8 + jo] = (f16)acc[Tl][r];
        }
    }
    __syncthreads();

    // ---- build cand A-frags in registers: A[m=o_own][kk=l], 7 chunks of 8 l
    //      strided u16 reads from row-frag (one-time); l>=208 -> 0
    f16x8 mfrag[LKS];
    #pragma unroll
    for (int ks = 0; ks < LKS; ks++) {
        f16x8 h;
        #pragma unroll
        for (int j = 0; j < 8; j++) {
            int l = ks*32 + q*8 + j;
            f16 v = (f16)0.f;
            if (l < 208) {
                int Tl = l >> 4, lp = l & 15;
                v = m_sw[((Tl*2 + kso)*64 + qo*16 + lp)*8 + jo];
            }
            h[j] = v;
        }
        mfrag[ks] = h;
    }

    // ---- routing: 3 iterations (2 with logits update, last writes output)
    for (int iter = 0; iter < 3; iter++) {
        // softmax over k (3 capsules) per position l; masked l -> uniform 1/3
        if (t < LSEQ) {
            float w0, w1, w2;
            if (t < s) {
                float l0 = logits[t], l1 = logits[LSEQ + t], l2 = logits[2*LSEQ + t];
                float mx = fmaxf(fmaxf(l0, l1), l2);
                float e0 = expf(l0 - mx), e1 = expf(l1 - mx), e2 = expf(l2 - mx);
                float inv = 1.f / (e0 + e1 + e2);
                w0 = e0*inv; w1 = e1*inv; w2 = e2*inv;
            } else {
                w0 = w1 = w2 = (1.f/3.f);
            }
            int ks = t >> 5, qq = (t & 31) >> 3, j = t & 7;
            int base = (ks*64 + qq*16)*8 + j;
            w_sw[base]      = (f16)w0;
            w_sw[base + 8]  = (f16)w1;
            w_sw[base + 16] = (f16)w2;
        }
        __syncthreads();

        // cand^T[o][k] = sum_l m[l][o]*w[k][l]  (MFMA: A=mfrag regs, B=w_sw)
        f32x4 ca = {0.f, 0.f, 0.f, 0.f};
        #pragma unroll
        for (int ks = 0; ks < LKS; ks++) {
            f16x8 b = *(f16x8*)&w_sw[(ks*64 + lane)*8];
            ca = __builtin_amdgcn_mfma_f32_16x16x32_f16(mfrag[ks], b, ca, 0, 0, 0);
        }
        // D[m=o][n=caps]: col=cc=capsule, row=q*4+r = o within tile
        if (cc < 3) {
            #pragma unroll
            for (int r = 0; r < 4; r++) cand[cc*64 + wv*16 + q*4 + r] = ca[r];
        }
        __syncthreads();

        // squash per capsule k (waves 0..2), write interests or final output
        if (t < 192) {
            float x = cand[t];
            float sq = x*x;
            #pragma unroll
            for (int off = 32; off >= 1; off >>= 1) sq += __shfl_xor(sq, off, 64);
            float factor = sq / ((1.f + sq) * sqrtf(sq + 1e-8f));
            float y = factor * x;
            if (iter < 2) {
                int k = t >> 6, o = t & 63;
                i_sw[(((o >> 5)*4 + ((o & 31) >> 3))*16 + k)*8 + (o & 7)] = (f16)y;
            } else {
                out[(size_t)n*192 + t] = y;
            }
        }
        if (iter == 2) break;
        __syncthreads();

        // logits[k][l] += sum_o interests[k][o]*m[l][o]  (MFMA, B=row-frag m)
        for (int Tn = wv; Tn < LT; Tn += 4) {
            f32x4 da = {0.f, 0.f, 0.f, 0.f};
            #pragma unroll
            for (int ko = 0; ko < 2; ko++) {
                f16x8 a = *(f16x8*)&i_sw[(ko*64 + lane)*8];
                f16x8 b = *(f16x8*)&m_sw[((Tn*2 + ko)*64 + lane)*8];
                da = __builtin_amdgcn_mfma_f32_16x16x32_f16(a, b, da, 0, 0, 0);
            }
            if (lane < 16) {
                int l = Tn*16 + lane;
                if (l < LSEQ) {
                    logits[l]          += da[0];
                    logits[LSEQ + l]   += da[1];
                    logits[2*LSEQ + l] += da[2];
                }
            }
        }
        __syncthreads();
    }
}

extern "C" void kernel_launch(void* const* d_in, const int* in_sizes, int n_in,
                              void* d_out, int out_size, void* d_ws, size_t ws_size,
                              hipStream_t stream) {
    const float* E  = (const float*)d_in[0];
    const float* W  = (const float*)d_in[1];
    const float* RL = (const float*)d_in[2];
    const int*   SL = (const int*)d_in[3];
    float* o = (float*)d_out;
    const int N = in_sizes[3];   // seq_len has N entries
    capsule_kernel<<<dim3(N), dim3(256), 0, stream>>>(E, W, RL, SL, o);
}